// Round 3
// baseline (3345.798 us; speedup 1.0000x reference)
//
#include <hip/hip_runtime.h>
#include <math.h>

// Problem constants (match reference)
#define NB   32
#define NA   24564
#define NTOT (NB * NA)          // 786048 = 128 * 6141 exactly
#define NCH  85                 // 4 box deltas + 81 logits
#define TOPK 200
#define IOU_THR_F     0.5f
#define SCORE_FLOOR_F 0.01f

#define DEC_T 128               // decode block size (exact divisor of NTOT)
#define NMS_T 512               // nms block size
#define SLOTS ((NA + NMS_T - 1) / NMS_T)   // 48 anchors per thread

// ---------------------------------------------------------------------------
// Kernel 1: decode boxes + softmax score/cls per anchor.
// LDS-staged coalesced input; per-thread arithmetic BIT-IDENTICAL to the
// R1-passing version (strict __f*_rn, exp in double).
// ---------------------------------------------------------------------------
__global__ __launch_bounds__(DEC_T) void decode_kernel(
    const float* __restrict__ x, const float* __restrict__ anchor,
    float4* __restrict__ boxes, float* __restrict__ scores,
    float* __restrict__ clsf)
{
    __shared__ float tile[DEC_T * NCH];            // 43,520 B -> 3 blocks/CU

    const int base = blockIdx.x * DEC_T;
    const float4* src = (const float4*)(x + (size_t)base * NCH);
    float4* dst = (float4*)tile;
    for (int k = threadIdx.x; k < DEC_T * NCH / 4; k += DEC_T) dst[k] = src[k];
    __syncthreads();

    const int g = base + threadIdx.x;
    const int i = g % NA;
    const float* row = tile + threadIdx.x * NCH;

    float ax = anchor[i * 4 + 0];
    float ay = anchor[i * 4 + 1];
    float aw = anchor[i * 4 + 2];
    float ah = anchor[i * 4 + 3];

    float d0 = row[0], d1 = row[1], d2 = row[2], d3 = row[3];
    float cx = __fadd_rn(__fdiv_rn(__fmul_rn(d0, aw), 10.0f), ax);
    float cy = __fadd_rn(__fdiv_rn(__fmul_rn(d1, ah), 10.0f), ay);
    float w = __fmul_rn((float)exp((double)__fdiv_rn(d2, 5.0f)), aw);
    float h = __fmul_rn((float)exp((double)__fdiv_rn(d3, 5.0f)), ah);
    float hw = __fmul_rn(w, 0.5f);
    float hh = __fmul_rn(h, 0.5f);
    boxes[g] = make_float4(__fsub_rn(cx, hw), __fsub_rn(cy, hh),
                           __fadd_rn(cx, hw), __fadd_rn(cy, hh));

    const float* z = row + 4;
    float m = z[0];
    #pragma unroll 9
    for (int k = 1; k < 81; k++) m = fmaxf(m, z[k]);

    double S = 0.0;
    double be = 0.0;
    float  bz = -INFINITY;
    int    bj = 0;
    for (int k = 0; k < 81; k++) {
        float zk = z[k];
        double e = exp((double)__fsub_rn(zk, m));
        S += e;
        if (k >= 1 && zk > bz) { bz = zk; be = e; bj = k - 1; }
    }
    scores[g] = (float)(be / S);
    clsf[g]   = (float)bj;
}

// ---------------------------------------------------------------------------
// Kernel 2: per-batch greedy NMS, one 512-thread block per batch.
// Boxes in registers (48/thread), aliveness as a u64 register mask, scores in
// LDS. Suppression vs previous winner is FUSED into the argmax scan.
// CRITICAL (R2 bug): the winner must be killed EXPLICITLY — reference IoU
// clips intersection extents to [0,1] but not areas, so self-IoU < 0.5 for
// boxes with w>1 or h>1; relying on IoU for self-removal re-selects them
// forever. Owner thread clears the winner's alive bit after selection.
// ---------------------------------------------------------------------------
__global__ __launch_bounds__(NMS_T) void nms_kernel(
    const float4* __restrict__ boxes, const float* __restrict__ scores,
    const float* __restrict__ clsf, float* __restrict__ out)
{
    __shared__ float s_score[NA];                  // 98,256 B
    __shared__ unsigned long long s_best[2];

    const int b   = blockIdx.x;
    const int tid = threadIdx.x;
    const float*  sc = scores + (size_t)b * NA;
    const float4* bx = boxes  + (size_t)b * NA;
    const float*  cf = clsf   + (size_t)b * NA;
    float* ob = out + (size_t)b * TOPK * 6;

    float4 box[SLOTS];
    unsigned long long alive = 0ULL;
    #pragma unroll
    for (int s = 0; s < SLOTS; s++) {
        int j = tid + s * NMS_T;
        if (j < NA) { box[s] = bx[j]; alive |= (1ULL << s); }
    }
    for (int j = tid; j < NA; j += NMS_T) s_score[j] = sc[j];
    if (tid < 2) s_best[tid] = 0ULL;
    __syncthreads();

    // dummy chosen for iteration 0: zero overlap with any real box, area 1
    float4 ch = make_float4(-1000000.0f, -1000000.0f, -999999.0f, -999999.0f);

    int t = 0;
    for (; t < TOPK; t++) {
        const float a1 = __fmul_rn(__fsub_rn(ch.z, ch.x), __fsub_rn(ch.w, ch.y));
        unsigned long long bestk = 0ULL;
        #pragma unroll
        for (int s = 0; s < SLOTS; s++) {
            if (alive & (1ULL << s)) {
                float4 v = box[s];
                float area2  = __fmul_rn(__fsub_rn(v.z, v.x), __fsub_rn(v.w, v.y));
                float xl = fmaxf(ch.x, v.x);
                float xr = fminf(ch.z, v.z);
                float yt = fmaxf(ch.y, v.y);
                float yb = fminf(ch.w, v.w);
                float cw = fminf(fmaxf(__fsub_rn(xr, xl), 0.0f), 1.0f);
                float chh = fminf(fmaxf(__fsub_rn(yb, yt), 0.0f), 1.0f);
                float common = __fmul_rn(cw, chh);
                float denom  = __fsub_rn(__fadd_rn(a1, area2), common);
                float iou    = __fdiv_rn(common, denom);
                if (!(iou < IOU_THR_F)) {
                    alive &= ~(1ULL << s);          // suppressed by prev winner
                } else {
                    int j = tid + s * NMS_T;
                    unsigned long long key =
                        ((unsigned long long)__float_as_uint(s_score[j]) << 32) |
                        (unsigned int)(NA - j);
                    if (key > bestk) bestk = key;
                }
            }
        }
        #pragma unroll
        for (int off = 32; off > 0; off >>= 1) {
            unsigned long long o = __shfl_down(bestk, off, 64);
            if (o > bestk) bestk = o;
        }
        if ((tid & 63) == 0) atomicMax(&s_best[t & 1], bestk);
        __syncthreads();

        unsigned long long wk = s_best[t & 1];
        float bscore = __uint_as_float((unsigned int)(wk >> 32));
        if (!(bscore >= SCORE_FLOOR_F)) break;      // exhausted (ref emits zeros)
        int widx = NA - (int)(wk & 0xFFFFFFFFu);

        // EXPLICIT winner kill (matches ref valid.at[idx].set(False)) — do NOT
        // rely on self-IoU: clipped-intersection self-IoU can be < 0.5.
        if (tid == (widx & (NMS_T - 1))) alive &= ~(1ULL << (widx / NMS_T));

        float4 wb = bx[widx];                       // same-address broadcast load
        if (tid == 0) {
            ob[t * 6 + 0] = cf[widx];
            ob[t * 6 + 1] = bscore;
            ob[t * 6 + 2] = wb.x;
            ob[t * 6 + 3] = wb.y;
            ob[t * 6 + 4] = wb.z;
            ob[t * 6 + 5] = wb.w;
            s_best[(t + 1) & 1] = 0ULL;             // reset next iter's buffer
        }
        ch = wb;                                    // suppress vs this next iter
        __syncthreads();
    }

    for (int k = t * 6 + tid; k < TOPK * 6; k += NMS_T) ob[k] = 0.0f;
}

// ---------------------------------------------------------------------------
extern "C" void kernel_launch(void* const* d_in, const int* in_sizes, int n_in,
                              void* d_out, int out_size, void* d_ws, size_t ws_size,
                              hipStream_t stream) {
    const float* x      = (const float*)d_in[0];   // (32, 24564, 85)
    const float* anchor = (const float*)d_in[1];   // (24564, 4)
    float* out = (float*)d_out;                    // (32, 200, 6)

    char* ws = (char*)d_ws;
    const size_t boxes_bytes  = (size_t)NTOT * 16;
    const size_t scores_off   = (boxes_bytes + 255) & ~255ULL;
    const size_t scores_bytes = (size_t)NTOT * 4;
    const size_t cls_off      = (scores_off + scores_bytes + 255) & ~255ULL;

    float4* boxes  = (float4*)ws;
    float*  scores = (float*)(ws + scores_off);
    float*  clsf   = (float*)(ws + cls_off);

    decode_kernel<<<NTOT / DEC_T, DEC_T, 0, stream>>>(x, anchor, boxes, scores, clsf);
    nms_kernel<<<NB, NMS_T, 0, stream>>>(boxes, scores, clsf, out);
}

// Round 4
// 2489.006 us; speedup vs baseline: 1.3442x; 1.3442x over previous
//
#include <hip/hip_runtime.h>
#include <math.h>

// Problem constants (match reference)
#define NB   32
#define NA   24564
#define NTOT (NB * NA)          // 786048 = 128 * 6141 exactly
#define NCH  85                 // 4 box deltas + 81 logits
#define TOPK 200
#define IOU_THR_F     0.5f
#define SCORE_FLOOR_F 0.01f

#define DEC_T 128               // decode block size (exact divisor of NTOT)
#define NMS_T 512               // nms block size
#define SLOTS ((NA + NMS_T - 1) / NMS_T)   // 48 anchors per thread

// ---------------------------------------------------------------------------
// Kernel 1: decode boxes + softmax score/cls per anchor.
// LDS-staged coalesced input; per-thread arithmetic BIT-IDENTICAL to the
// R1-passing version (strict __f*_rn, exp in double). DO NOT alter numerics.
// ---------------------------------------------------------------------------
__global__ __launch_bounds__(DEC_T) void decode_kernel(
    const float* __restrict__ x, const float* __restrict__ anchor,
    float4* __restrict__ boxes, float* __restrict__ scores,
    float* __restrict__ clsf)
{
    __shared__ float tile[DEC_T * NCH];            // 43,520 B -> 3 blocks/CU

    const int base = blockIdx.x * DEC_T;
    const float4* src = (const float4*)(x + (size_t)base * NCH);
    float4* dst = (float4*)tile;
    for (int k = threadIdx.x; k < DEC_T * NCH / 4; k += DEC_T) dst[k] = src[k];
    __syncthreads();

    const int g = base + threadIdx.x;
    const int i = g % NA;
    const float* row = tile + threadIdx.x * NCH;

    float ax = anchor[i * 4 + 0];
    float ay = anchor[i * 4 + 1];
    float aw = anchor[i * 4 + 2];
    float ah = anchor[i * 4 + 3];

    float d0 = row[0], d1 = row[1], d2 = row[2], d3 = row[3];
    float cx = __fadd_rn(__fdiv_rn(__fmul_rn(d0, aw), 10.0f), ax);
    float cy = __fadd_rn(__fdiv_rn(__fmul_rn(d1, ah), 10.0f), ay);
    float w = __fmul_rn((float)exp((double)__fdiv_rn(d2, 5.0f)), aw);
    float h = __fmul_rn((float)exp((double)__fdiv_rn(d3, 5.0f)), ah);
    float hw = __fmul_rn(w, 0.5f);
    float hh = __fmul_rn(h, 0.5f);
    boxes[g] = make_float4(__fsub_rn(cx, hw), __fsub_rn(cy, hh),
                           __fadd_rn(cx, hw), __fadd_rn(cy, hh));

    const float* z = row + 4;
    float m = z[0];
    #pragma unroll 9
    for (int k = 1; k < 81; k++) m = fmaxf(m, z[k]);

    double S = 0.0;
    double be = 0.0;
    float  bz = -INFINITY;
    int    bj = 0;
    for (int k = 0; k < 81; k++) {
        float zk = z[k];
        double e = exp((double)__fsub_rn(zk, m));
        S += e;
        if (k >= 1 && zk > bz) { bz = zk; be = e; bj = k - 1; }
    }
    scores[g] = (float)(be / S);
    clsf[g]   = (float)bj;
}

// ---------------------------------------------------------------------------
// Kernel 2: per-batch greedy NMS, one 512-thread block per batch.
// Boxes in registers (48/thread = 192 VGPR), aliveness as a u64 register
// mask, scores in LDS. Suppression vs previous winner FUSED into the argmax
// scan: one pass + 2 barriers per selection.
// __launch_bounds__(512, 1) is LOAD-BEARING: without it the compiler caps
// at 128 VGPRs and spills the box array to scratch (R3: 11.2 GB FETCH,
// 2880 µs). LDS (98 KB) limits to 1 block/CU -> 2 waves/SIMD -> 256 VGPR
// budget, which fits 192 + overhead.
// CRITICAL (R2 bug): winner is killed EXPLICITLY — ref IoU clips
// intersection extents to [0,1] but not areas, so self-IoU can be < 0.5.
// ---------------------------------------------------------------------------
__global__ __launch_bounds__(NMS_T, 1) void nms_kernel(
    const float4* __restrict__ boxes, const float* __restrict__ scores,
    const float* __restrict__ clsf, float* __restrict__ out)
{
    __shared__ float s_score[NA];                  // 98,256 B
    __shared__ unsigned long long s_best[2];

    const int b   = blockIdx.x;
    const int tid = threadIdx.x;
    const float*  sc = scores + (size_t)b * NA;
    const float4* bx = boxes  + (size_t)b * NA;
    const float*  cf = clsf   + (size_t)b * NA;
    float* ob = out + (size_t)b * TOPK * 6;

    float4 box[SLOTS];
    unsigned long long alive = 0ULL;
    #pragma unroll
    for (int s = 0; s < SLOTS; s++) {
        int j = tid + s * NMS_T;
        if (j < NA) { box[s] = bx[j]; alive |= (1ULL << s); }
    }
    for (int j = tid; j < NA; j += NMS_T) s_score[j] = sc[j];
    if (tid < 2) s_best[tid] = 0ULL;
    __syncthreads();

    // dummy chosen for iteration 0: zero overlap with any real box, area 1
    float4 ch = make_float4(-1000000.0f, -1000000.0f, -999999.0f, -999999.0f);

    int t = 0;
    for (; t < TOPK; t++) {
        const float a1 = __fmul_rn(__fsub_rn(ch.z, ch.x), __fsub_rn(ch.w, ch.y));
        float bs = 0.0f;          // scores are strictly positive
        int   bj = NA;            // sentinel: (NA - bj) == 0
        #pragma unroll
        for (int s = 0; s < SLOTS; s++) {
            if (alive & (1ULL << s)) {
                float4 v = box[s];
                float area2  = __fmul_rn(__fsub_rn(v.z, v.x), __fsub_rn(v.w, v.y));
                float xl = fmaxf(ch.x, v.x);
                float xr = fminf(ch.z, v.z);
                float yt = fmaxf(ch.y, v.y);
                float yb = fminf(ch.w, v.w);
                float cw = fminf(fmaxf(__fsub_rn(xr, xl), 0.0f), 1.0f);
                float chh = fminf(fmaxf(__fsub_rn(yb, yt), 0.0f), 1.0f);
                float common = __fmul_rn(cw, chh);
                float denom  = __fsub_rn(__fadd_rn(a1, area2), common);
                float iou    = __fdiv_rn(common, denom);
                if (!(iou < IOU_THR_F)) {
                    alive &= ~(1ULL << s);          // suppressed by prev winner
                } else {
                    int j = tid + s * NMS_T;
                    float sscore = s_score[j];
                    // strict > keeps smallest j on within-thread ties
                    if (sscore > bs) { bs = sscore; bj = j; }
                }
            }
        }
        // pack once: max score, tie -> smallest index (largest NA-j)
        unsigned long long bestk =
            ((unsigned long long)__float_as_uint(bs) << 32) |
            (unsigned int)(NA - bj);
        #pragma unroll
        for (int off = 32; off > 0; off >>= 1) {
            unsigned long long o = __shfl_down(bestk, off, 64);
            if (o > bestk) bestk = o;
        }
        if ((tid & 63) == 0) atomicMax(&s_best[t & 1], bestk);
        __syncthreads();

        unsigned long long wk = s_best[t & 1];
        float bscore = __uint_as_float((unsigned int)(wk >> 32));
        if (!(bscore >= SCORE_FLOOR_F)) break;      // exhausted (ref emits zeros)
        int widx = NA - (int)(wk & 0xFFFFFFFFu);

        // EXPLICIT winner kill (matches ref valid.at[idx].set(False))
        if (tid == (widx & (NMS_T - 1))) alive &= ~(1ULL << (widx / NMS_T));

        float4 wb = bx[widx];                       // same-address broadcast load
        if (tid == 0) {
            ob[t * 6 + 0] = cf[widx];
            ob[t * 6 + 1] = bscore;
            ob[t * 6 + 2] = wb.x;
            ob[t * 6 + 3] = wb.y;
            ob[t * 6 + 4] = wb.z;
            ob[t * 6 + 5] = wb.w;
            s_best[(t + 1) & 1] = 0ULL;             // reset next iter's buffer
        }
        ch = wb;                                    // suppress vs this next iter
        __syncthreads();
    }

    for (int k = t * 6 + tid; k < TOPK * 6; k += NMS_T) ob[k] = 0.0f;
}

// ---------------------------------------------------------------------------
extern "C" void kernel_launch(void* const* d_in, const int* in_sizes, int n_in,
                              void* d_out, int out_size, void* d_ws, size_t ws_size,
                              hipStream_t stream) {
    const float* x      = (const float*)d_in[0];   // (32, 24564, 85)
    const float* anchor = (const float*)d_in[1];   // (24564, 4)
    float* out = (float*)d_out;                    // (32, 200, 6)

    char* ws = (char*)d_ws;
    const size_t boxes_bytes  = (size_t)NTOT * 16;
    const size_t scores_off   = (boxes_bytes + 255) & ~255ULL;
    const size_t scores_bytes = (size_t)NTOT * 4;
    const size_t cls_off      = (scores_off + scores_bytes + 255) & ~255ULL;

    float4* boxes  = (float4*)ws;
    float*  scores = (float*)(ws + scores_off);
    float*  clsf   = (float*)(ws + cls_off);

    decode_kernel<<<NTOT / DEC_T, DEC_T, 0, stream>>>(x, anchor, boxes, scores, clsf);
    nms_kernel<<<NB, NMS_T, 0, stream>>>(boxes, scores, clsf, out);
}